// Round 19
// baseline (52.328 us; speedup 1.0000x reference)
//
#include <hip/hip_runtime.h>
#include <cfloat>
#include <cstdint>

#define NSEG 512
#define C 21
#define PPB 512                   // points per chunk
#define EPS_PICK 1e-3f            // >= 2*deltaM (f16-split emu err ~2e-5) and >= deltaM+delta32
#define SLACK 1.5e-4f             // covers 16-ULP(|v|<64) aux quantization of L (6.1e-5)

typedef _Float16 half8 __attribute__((ext_vector_type(8)));   // 8 f16 (MFMA A/B frag)
typedef float f32x16 __attribute__((ext_vector_type(16)));    // 32x32 MFMA acc

// ===================== K1: scatter + self-staged f16 MFMA (R17-validated, verbatim) =====================
__global__ __launch_bounds__(256, 4)
void k1_mfma_scatter(const float* __restrict__ pts, const float* __restrict__ dpts,
                     const int* __restrict__ sptids,
                     float4* __restrict__ pts4, float* __restrict__ pbvT,
                     unsigned* __restrict__ auxT,
                     int* __restrict__ segbase, int* __restrict__ sorted_orig,
                     float* __restrict__ out, int n, int m, int NCH)
{
    __shared__ half8 lbuf[1024];                  // 16 KB (A-chunk / scatter scratch)
    const int bid = blockIdx.x, t = threadIdx.x;

    if (bid < NCH) {
        // ---- scatter chunk sb: stable counting sort (R12-R18 validated, verbatim) ----
        int sb = bid;
        int* Hb   = (int*)lbuf;
        int* Ht   = Hb + NSEG;
        int* pair = Ht + NSEG;
        int* segs = pair + 256;
        Hb[t] = 0; Hb[t + 256] = 0; Ht[t] = 0; Ht[t + 256] = 0;
        __syncthreads();
        int before = sb * 256;
        for (int idx = t; idx < m; idx += 256) {
            int s = sptids[idx];
            atomicAdd(&Ht[s], 1);
            if (idx < before) atomicAdd(&Hb[s], 1);
        }
        __syncthreads();
        int e0 = Ht[2 * t], e1 = Ht[2 * t + 1];
        int v = e0 + e1;
        pair[t] = v;
        __syncthreads();
        for (int off = 1; off < 256; off <<= 1) {
            int add = (t >= off) ? pair[t - off] : 0;
            __syncthreads();
            v += add; pair[t] = v;
            __syncthreads();
        }
        int prev = (t > 0) ? pair[t - 1] : 0;
        int b0 = prev, b1 = prev + e0;
        if (sb == 0) { segbase[2 * t] = b0; segbase[2 * t + 1] = b1; }
        int hb0 = Hb[2 * t], hb1 = Hb[2 * t + 1];
        __syncthreads();
        Hb[2 * t] = b0 + hb0;
        Hb[2 * t + 1] = b1 + hb1;
        int i = sb * 256 + t;
        segs[t] = (i < m) ? sptids[i] : -1;
        __syncthreads();
        if (i < m) {
            int seg = segs[t];
            int rank = 0;
            for (int j = 0; j < t; j++) rank += (segs[j] == seg) ? 1 : 0;
            int pos = Hb[seg] + rank;
            out[pos * 3 + 0] = dpts[i * 3 + 0];
            out[pos * 3 + 1] = dpts[i * 3 + 1];
            out[pos * 3 + 2] = dpts[i * 3 + 2];
            sorted_orig[pos] = i;
        }
        return;
    }

    // ---- MFMA block ----
    const int b2 = bid - NCH;
    const int qb = b2 & 31, pc = b2 >> 5;
    const int wave = t >> 6, lane = t & 63;
    const int g = lane >> 5, col = lane & 31;

    half8 bq[4];                                  // B-frags from raw dpts
#pragma unroll
    for (int k = 0; k < 4; k++) {
        int q = (qb * 16 + wave * 4 + k) * 32 + col;
        float b0 = dpts[q * 3 + 0], b1 = dpts[q * 3 + 1], b2c = dpts[q * 3 + 2];
        _Float16 bh0 = (_Float16)b0; _Float16 bl0 = (_Float16)(b0 - (float)bh0);
        _Float16 bh1 = (_Float16)b1; _Float16 bl1 = (_Float16)(b1 - (float)bh1);
        _Float16 bh2 = (_Float16)b2c; _Float16 bl2 = (_Float16)(b2c - (float)bh2);
        const _Float16 one = (_Float16)1.f, zz = (_Float16)0.f;
        half8 g0 = {bh0, bl0, bh0, bh1, bl1, bh1, bh2, bl2};
        half8 g1 = {bh2, one, one, zz, zz, zz, zz, zz};
        bq[k] = g ? g1 : g0;
    }

#pragma unroll
    for (int half = 0; half < 2; half++) {        // stage points t, t+256 of chunk pc
        int j = half * 256 + t;
        int i = pc * PPB + j;
        float x = pts[i * 3 + 0], y = pts[i * 3 + 1], z = pts[i * 3 + 2];
        if (qb == 0)
            pts4[i] = make_float4(x, y, z, fmaf(x, x, fmaf(y, y, z * z)));
        float a0 = -2.f * x, a1 = -2.f * y, a2 = -2.f * z;
        _Float16 ah0 = (_Float16)a0; _Float16 al0 = (_Float16)(a0 - (float)ah0);
        _Float16 ah1 = (_Float16)a1; _Float16 al1 = (_Float16)(a1 - (float)ah1);
        _Float16 ah2 = (_Float16)a2; _Float16 al2 = (_Float16)(a2 - (float)ah2);
        double ps = (double)x * x + (double)y * y + (double)z * z;
        _Float16 s0 = (_Float16)(float)ps;
        double r1 = ps - (double)(float)s0;
        _Float16 s1 = (_Float16)(float)r1;
        half8 g0 = {ah0, ah0, al0, ah1, ah1, al1, ah2, ah2};
        half8 g1 = {al2, s0, s1, (_Float16)0.f, (_Float16)0.f,
                    (_Float16)0.f, (_Float16)0.f, (_Float16)0.f};
        int base = (j >> 5) * 64 + (j & 31) * 2;
        lbuf[base + 0] = g0;
        lbuf[base + 1] = g1;
    }
    __syncthreads();

    // ---- MFMA loop with per-tile (run1, run2, tti) tracking ----
    float run1[4], run2[4];
    int ttix[4];
#pragma unroll
    for (int k = 0; k < 4; k++) { run1[k] = FLT_MAX; run2[k] = FLT_MAX; ttix[k] = 0; }
    const f32x16 zero = {0.f,0.f,0.f,0.f,0.f,0.f,0.f,0.f,0.f,0.f,0.f,0.f,0.f,0.f,0.f,0.f};
    const int aoff = col * 2 + g;

#pragma unroll 4
    for (int tt = 0; tt < 16; tt++) {
        half8 a = lbuf[tt * 64 + aoff];           // 16B b128, conflict-free
        f32x16 c0 = __builtin_amdgcn_mfma_f32_32x32x16_f16(a, bq[0], zero, 0, 0, 0);
        f32x16 c1 = __builtin_amdgcn_mfma_f32_32x32x16_f16(a, bq[1], zero, 0, 0, 0);
        f32x16 c2 = __builtin_amdgcn_mfma_f32_32x32x16_f16(a, bq[2], zero, 0, 0, 0);
        f32x16 c3 = __builtin_amdgcn_mfma_f32_32x32x16_f16(a, bq[3], zero, 0, 0, 0);
#define FOLD(cc, kk)  { \
        float v = fminf(fminf(cc[0], cc[1]), cc[2]);   \
        v = fminf(fminf(v, cc[3]), cc[4]);             \
        v = fminf(fminf(v, cc[5]), cc[6]);             \
        v = fminf(fminf(v, cc[7]), cc[8]);             \
        v = fminf(fminf(v, cc[9]), cc[10]);            \
        v = fminf(fminf(v, cc[11]), cc[12]);           \
        v = fminf(fminf(v, cc[13]), cc[14]);           \
        v = fminf(v, cc[15]);                          \
        float nr2 = fminf(run2[kk], fmaxf(v, run1[kk])); \
        if (v < run1[kk]) { ttix[kk] = tt; run1[kk] = v; } \
        run2[kk] = nr2; }
        FOLD(c0, 0) FOLD(c1, 1) FOLD(c2, 2) FOLD(c3, 3)
#undef FOLD
    }

    // ---- cross-half merge: chunk min r1c, winner tile T*, lower bound L on other tiles ----
#pragma unroll
    for (int k = 0; k < 4; k++) {
        float o1 = __shfl_xor(run1[k], 32, 64);
        float o2 = __shfl_xor(run2[k], 32, 64);
        int   ot = __shfl_xor(ttix[k], 32, 64);
        float lo1 = (lane < 32) ? run1[k] : o1;  int loT = (lane < 32) ? ttix[k] : ot;
        float lo2 = (lane < 32) ? run2[k] : o2;
        float hi1 = (lane < 32) ? o1 : run1[k];  int hiT = (lane < 32) ? ot : ttix[k];
        float hi2 = (lane < 32) ? o2 : run2[k];
        float r1c = fminf(lo1, hi1);
        int Tstar = (lo1 <= hi1) ? loT : hiT;
        float cl = (loT != Tstar) ? lo1 : lo2;
        float ch = (hiT != Tstar) ? hi1 : hi2;
        float L = fminf(cl, ch);
        if (lane < 32) {
            size_t qi = (size_t)(qb * 512 + wave * 128 + k * 32 + lane) * 64 + pc;
            pbvT[qi] = r1c;
            auxT[qi] = (__float_as_uint(L) & ~0xFu) | (unsigned)Tstar;
        }
    }
}

// ===================== K1.5: gmask — thread-per-query gmin + chunk mask =====================
// 128 blocks x 512 thr; block handles 128 queries. Stream the contiguous 32 KB pbvT
// slab (coalesced float4), LDS-tile with +1 pad (conflict-free rows), then thread tq:
// g1 = min(row), mask bit pc set iff row[pc] <= g1+EPS — BIT-IDENTICAL to the old
// in-wave butterfly+ballot (same values, same compare).
__global__ __launch_bounds__(512)
void gmask(const float* __restrict__ pbvT, float* __restrict__ gmin,
           unsigned long long* __restrict__ qmask, int m)
{
    __shared__ float lt[128 * 65];                // 128 rows, stride 65 (pad +1)
    const int t = threadIdx.x;
    const int q0 = blockIdx.x * 128;

    const float4* src = (const float4*)(pbvT + (size_t)q0 * 64);
#pragma unroll
    for (int r = 0; r < 4; r++) {                 // 2048 float4 = 32 KB, coalesced
        int f4 = t + r * 512;
        float4 v = src[f4];
        int gidx = f4 * 4;
        int q = gidx >> 6, pc = gidx & 63;
        float* row = lt + q * 65 + pc;
        row[0] = v.x; row[1] = v.y; row[2] = v.z; row[3] = v.w;
    }
    __syncthreads();

    if (t < 128) {
        const float* row = lt + t * 65;
        float g1 = row[0];
#pragma unroll 8
        for (int i = 1; i < 64; i++) g1 = fminf(g1, row[i]);
        float thr = g1 + EPS_PICK;
        unsigned long long msk = 0;
#pragma unroll 8
        for (int i = 0; i < 64; i++)
            if (row[i] <= thr) msk |= 1ull << i;
        gmin[q0 + t] = g1;
        qmask[q0 + t] = msk;
    }
}

// ===================== K2: seg_pick_final (16 waves; gmin/qmask front-end) =====================
// One block per segment, 16 waves. Per member q: g1/mask are two lane-uniform loads
// (replacing the 256B row gather + butterfly — values bit-identical). Then the
// R17-validated narrowed resolve: per qualifying chunk, auxT narrowing
// (L > thr+SLACK -> scan tile T*, 32 pts) else full 512-pt scan; f32 filter ->
// exact f64 eval; lowest-index tie-break == full f64 argmin. Lane c<21 accumulates
// scores[nn][c] in f64, fixed (j,wave) order -> deterministic; block argmax
// (strict >) -> labels to original positions.
__global__ __launch_bounds__(1024)
void k2_seg_pick(const float4* __restrict__ pts4, const float* __restrict__ dpts,
                 const float* __restrict__ scores, const float* __restrict__ gmin,
                 const unsigned long long* __restrict__ qmask,
                 const unsigned* __restrict__ auxT,
                 const int* __restrict__ segbase, const int* __restrict__ sorted_orig,
                 float* __restrict__ out, int n, int m)
{
    __shared__ double wsum[16][C];
    __shared__ double total[C];
    __shared__ float lab;
    const int t = threadIdx.x, wave = t >> 6, lane = t & 63;
    const int s = blockIdx.x;
    const int base = segbase[s];
    const int end  = (s == NSEG - 1) ? m : segbase[s + 1];

    double acc = 0.0;                             // channel `lane` partial (lanes 0..20)
    for (int j = base + wave; j < end; j += 16) {
        int q = sorted_orig[j];
        float g1 = gmin[q];                       // lane-uniform 4B
        unsigned long long msk = qmask[q];        // lane-uniform 8B
        float thr = g1 + EPS_PICK;

        float fx = dpts[q * 3 + 0], fy = dpts[q * 3 + 1], fz = dpts[q * 3 + 2];
        float fm2x = -2.f * fx, fm2y = -2.f * fy, fm2z = -2.f * fz;
        double m2x = -2.0 * (double)fx, m2y = -2.0 * (double)fy, m2z = -2.0 * (double)fz;
        double best = 1e308; int bi = 0x7fffffff;
        while (msk) {
            int pc = __builtin_ctzll(msk); msk &= msk - 1;
            unsigned au = auxT[(size_t)q * 64 + pc];     // lane-uniform -> broadcast
            float L = __uint_as_float(au & ~0xFu);
            int Ts = (int)(au & 0xFu);
            if (L > thr + SLACK) {
                if (lane < 32) {                  // only tile T* can hold candidates
                    int i = pc * PPB + Ts * 32 + lane;
                    if (i < n) {
                        float4 p = pts4[i];
                        float v = fmaf(p.x, fm2x, fmaf(p.y, fm2y, fmaf(p.z, fm2z, p.w)));
                        if (v <= thr) {
                            double ps = (double)p.x * p.x + (double)p.y * p.y + (double)p.z * p.z;
                            double dv = fma((double)p.x, m2x, fma((double)p.y, m2y,
                                        fma((double)p.z, m2z, ps)));
                            if (dv < best || (dv == best && i < bi)) { best = dv; bi = i; }
                        }
                    }
                }
            } else {
                int pbase = pc * PPB + lane;      // full chunk scan (validated path)
#pragma unroll
                for (int r2 = 0; r2 < PPB / 64; r2++) {
                    int i = pbase + r2 * 64;
                    if (i < n) {
                        float4 p = pts4[i];
                        float v = fmaf(p.x, fm2x, fmaf(p.y, fm2y, fmaf(p.z, fm2z, p.w)));
                        if (v <= thr) {
                            double ps = (double)p.x * p.x + (double)p.y * p.y + (double)p.z * p.z;
                            double dv = fma((double)p.x, m2x, fma((double)p.y, m2y,
                                        fma((double)p.z, m2z, ps)));
                            if (dv < best || (dv == best && i < bi)) { best = dv; bi = i; }
                        }
                    }
                }
            }
        }
#pragma unroll
        for (int off = 32; off; off >>= 1) {
            double ov = __shfl_down(best, off, 64);
            int oi = __shfl_down(bi, off, 64);
            if (ov < best || (ov == best && oi < bi)) { best = ov; bi = oi; }
        }
        int bi0 = __shfl(bi, 0, 64);
        if (lane < C)
            acc += (double)scores[(size_t)bi0 * C + lane];
    }
    if (lane < C) wsum[wave][lane] = acc;
    __syncthreads();
    if (t < C) {
        double tv = 0.0;
#pragma unroll
        for (int w = 0; w < 16; w++) tv += wsum[w][t];   // fixed wave order
        total[t] = tv;
    }
    __syncthreads();
    if (t == 0) {
        double bv = total[0]; int best = 0;
        for (int c = 1; c < C; c++)
            if (total[c] > bv) { bv = total[c]; best = c; }  // strict >: first max wins
        lab = (float)best;
    }
    __syncthreads();
    float fb = lab;
    for (int j = base + t; j < end; j += 1024)    // labels in ORIGINAL order
        out[(size_t)m * 3 + sorted_orig[j]] = fb;
}

extern "C" void kernel_launch(void* const* d_in, const int* in_sizes, int n_in,
                              void* d_out, int out_size, void* d_ws, size_t ws_size,
                              hipStream_t stream) {
    const float* points = (const float*)d_in[0];
    const float* scores = (const float*)d_in[1];
    const float* dpts   = (const float*)d_in[2];
    const int*   sptids = (const int*)d_in[3];

    int n = in_sizes[0] / 3;          // 32768
    int m = in_sizes[2] / 3;          // 16384
    int NCH   = (m + 255) / 256;      // 64 scatter chunks
    int QB    = (m + 511) / 512;      // 32 query blocks
    int PCg   = (n + 511) / 512;      // 64 point chunks
    int MFMAB = QB * PCg;             // 2048 mfma blocks

    char* ws = (char*)d_ws;
    float4*   pts4        = (float4*)ws;    ws += (size_t)n * sizeof(float4);
    float*    pbvT        = (float*)ws;     ws += (size_t)m * 64 * sizeof(float);
    unsigned* auxT        = (unsigned*)ws;  ws += (size_t)m * 64 * sizeof(unsigned);
    float*    gminb       = (float*)ws;     ws += (size_t)m * sizeof(float);
    unsigned long long* qmaskb = (unsigned long long*)ws; ws += (size_t)m * 8;
    int*      segbase     = (int*)ws;       ws += (size_t)NSEG * sizeof(int);
    int*      sorted_orig = (int*)ws;       ws += (size_t)m * sizeof(int);

    k1_mfma_scatter<<<NCH + MFMAB, 256, 0, stream>>>(points, dpts, sptids,
                                                     pts4, pbvT, auxT, segbase,
                                                     sorted_orig, (float*)d_out, n, m, NCH);
    gmask<<<m / 128, 512, 0, stream>>>(pbvT, gminb, qmaskb, m);
    k2_seg_pick<<<NSEG, 1024, 0, stream>>>(pts4, dpts, scores, gminb, qmaskb, auxT,
                                           segbase, sorted_orig, (float*)d_out, n, m);
}

// Round 20
// 46.931 us; speedup vs baseline: 1.1150x; 1.1150x over previous
//
#include <hip/hip_runtime.h>
#include <cfloat>
#include <cstdint>

#define NSEG 512
#define C 21
#define PPB 512                   // points per chunk
#define EPS_PICK 1e-3f            // >= 2*deltaM (f16-split emu err ~2e-5) and >= deltaM+delta32
#define SLACK 1.5e-4f             // covers 16-ULP(|v|<64) aux quantization of L (6.1e-5)

typedef _Float16 half8 __attribute__((ext_vector_type(8)));   // 8 f16 (MFMA A/B frag)
typedef float f32x16 __attribute__((ext_vector_type(16)));    // 32x32 MFMA acc

// ===================== K1: scatter + self-staged f16 MFMA (R17-validated, verbatim) =====================
// bid 0..63   : scatter chunk sb — stable counting sort of d_points; sb==0 writes segbase[].
// bid 64..2111: mfma block — self-stage chunk pc as f16 2-level-split slots (16 KB LDS),
//               B-frags for 128 queries/wave; 16 tt x 4 MFMA (32x32x16 f16);
//               per-query (run1, run2-of-tile-mins, T*) -> pbvT[q][pc]=chunk min,
//               auxT[q][pc]=(bits(L)&~0xF)|T* (L = lower bound on non-T* tile mins).
// K-slot layout (K=16, 11 used), per coord c (a=-2*p_c, b=q_c; ah/al = f16 Dekker):
//   slots 3c..3c+2: A=[ah,ah,al]  B=[bh,bl,bh]
//   slots 9,10:     A=[s0,s1] (|p|^2 2-level)  B=[1,1];  slots 11..15: 0
__global__ __launch_bounds__(256, 4)
void k1_mfma_scatter(const float* __restrict__ pts, const float* __restrict__ dpts,
                     const int* __restrict__ sptids,
                     float4* __restrict__ pts4, float* __restrict__ pbvT,
                     unsigned* __restrict__ auxT,
                     int* __restrict__ segbase, int* __restrict__ sorted_orig,
                     float* __restrict__ out, int n, int m, int NCH)
{
    __shared__ half8 lbuf[1024];                  // 16 KB (A-chunk / scatter scratch)
    const int bid = blockIdx.x, t = threadIdx.x;

    if (bid < NCH) {
        // ---- scatter chunk sb: stable counting sort (R12-R19 validated, verbatim) ----
        int sb = bid;
        int* Hb   = (int*)lbuf;
        int* Ht   = Hb + NSEG;
        int* pair = Ht + NSEG;
        int* segs = pair + 256;
        Hb[t] = 0; Hb[t + 256] = 0; Ht[t] = 0; Ht[t + 256] = 0;
        __syncthreads();
        int before = sb * 256;
        for (int idx = t; idx < m; idx += 256) {
            int s = sptids[idx];
            atomicAdd(&Ht[s], 1);
            if (idx < before) atomicAdd(&Hb[s], 1);
        }
        __syncthreads();
        int e0 = Ht[2 * t], e1 = Ht[2 * t + 1];
        int v = e0 + e1;
        pair[t] = v;
        __syncthreads();
        for (int off = 1; off < 256; off <<= 1) {
            int add = (t >= off) ? pair[t - off] : 0;
            __syncthreads();
            v += add; pair[t] = v;
            __syncthreads();
        }
        int prev = (t > 0) ? pair[t - 1] : 0;
        int b0 = prev, b1 = prev + e0;
        if (sb == 0) { segbase[2 * t] = b0; segbase[2 * t + 1] = b1; }
        int hb0 = Hb[2 * t], hb1 = Hb[2 * t + 1];
        __syncthreads();
        Hb[2 * t] = b0 + hb0;
        Hb[2 * t + 1] = b1 + hb1;
        int i = sb * 256 + t;
        segs[t] = (i < m) ? sptids[i] : -1;
        __syncthreads();
        if (i < m) {
            int seg = segs[t];
            int rank = 0;
            for (int j = 0; j < t; j++) rank += (segs[j] == seg) ? 1 : 0;
            int pos = Hb[seg] + rank;
            out[pos * 3 + 0] = dpts[i * 3 + 0];
            out[pos * 3 + 1] = dpts[i * 3 + 1];
            out[pos * 3 + 2] = dpts[i * 3 + 2];
            sorted_orig[pos] = i;
        }
        return;
    }

    // ---- MFMA block ----
    const int b2 = bid - NCH;
    const int qb = b2 & 31, pc = b2 >> 5;
    const int wave = t >> 6, lane = t & 63;
    const int g = lane >> 5, col = lane & 31;

    half8 bq[4];                                  // B-frags from raw dpts
#pragma unroll
    for (int k = 0; k < 4; k++) {
        int q = (qb * 16 + wave * 4 + k) * 32 + col;
        float b0 = dpts[q * 3 + 0], b1 = dpts[q * 3 + 1], b2c = dpts[q * 3 + 2];
        _Float16 bh0 = (_Float16)b0; _Float16 bl0 = (_Float16)(b0 - (float)bh0);
        _Float16 bh1 = (_Float16)b1; _Float16 bl1 = (_Float16)(b1 - (float)bh1);
        _Float16 bh2 = (_Float16)b2c; _Float16 bl2 = (_Float16)(b2c - (float)bh2);
        const _Float16 one = (_Float16)1.f, zz = (_Float16)0.f;
        half8 g0 = {bh0, bl0, bh0, bh1, bl1, bh1, bh2, bl2};
        half8 g1 = {bh2, one, one, zz, zz, zz, zz, zz};
        bq[k] = g ? g1 : g0;
    }

#pragma unroll
    for (int half = 0; half < 2; half++) {        // stage points t, t+256 of chunk pc
        int j = half * 256 + t;
        int i = pc * PPB + j;
        float x = pts[i * 3 + 0], y = pts[i * 3 + 1], z = pts[i * 3 + 2];
        if (qb == 0)
            pts4[i] = make_float4(x, y, z, fmaf(x, x, fmaf(y, y, z * z)));
        float a0 = -2.f * x, a1 = -2.f * y, a2 = -2.f * z;
        _Float16 ah0 = (_Float16)a0; _Float16 al0 = (_Float16)(a0 - (float)ah0);
        _Float16 ah1 = (_Float16)a1; _Float16 al1 = (_Float16)(a1 - (float)ah1);
        _Float16 ah2 = (_Float16)a2; _Float16 al2 = (_Float16)(a2 - (float)ah2);
        double ps = (double)x * x + (double)y * y + (double)z * z;
        _Float16 s0 = (_Float16)(float)ps;
        double r1 = ps - (double)(float)s0;
        _Float16 s1 = (_Float16)(float)r1;
        half8 g0 = {ah0, ah0, al0, ah1, ah1, al1, ah2, ah2};
        half8 g1 = {al2, s0, s1, (_Float16)0.f, (_Float16)0.f,
                    (_Float16)0.f, (_Float16)0.f, (_Float16)0.f};
        int base = (j >> 5) * 64 + (j & 31) * 2;
        lbuf[base + 0] = g0;
        lbuf[base + 1] = g1;
    }
    __syncthreads();

    // ---- MFMA loop with per-tile (run1, run2, tti) tracking ----
    float run1[4], run2[4];
    int ttix[4];
#pragma unroll
    for (int k = 0; k < 4; k++) { run1[k] = FLT_MAX; run2[k] = FLT_MAX; ttix[k] = 0; }
    const f32x16 zero = {0.f,0.f,0.f,0.f,0.f,0.f,0.f,0.f,0.f,0.f,0.f,0.f,0.f,0.f,0.f,0.f};
    const int aoff = col * 2 + g;

#pragma unroll 4
    for (int tt = 0; tt < 16; tt++) {
        half8 a = lbuf[tt * 64 + aoff];           // 16B b128, conflict-free
        f32x16 c0 = __builtin_amdgcn_mfma_f32_32x32x16_f16(a, bq[0], zero, 0, 0, 0);
        f32x16 c1 = __builtin_amdgcn_mfma_f32_32x32x16_f16(a, bq[1], zero, 0, 0, 0);
        f32x16 c2 = __builtin_amdgcn_mfma_f32_32x32x16_f16(a, bq[2], zero, 0, 0, 0);
        f32x16 c3 = __builtin_amdgcn_mfma_f32_32x32x16_f16(a, bq[3], zero, 0, 0, 0);
#define FOLD(cc, kk)  { \
        float v = fminf(fminf(cc[0], cc[1]), cc[2]);   \
        v = fminf(fminf(v, cc[3]), cc[4]);             \
        v = fminf(fminf(v, cc[5]), cc[6]);             \
        v = fminf(fminf(v, cc[7]), cc[8]);             \
        v = fminf(fminf(v, cc[9]), cc[10]);            \
        v = fminf(fminf(v, cc[11]), cc[12]);           \
        v = fminf(fminf(v, cc[13]), cc[14]);           \
        v = fminf(v, cc[15]);                          \
        float nr2 = fminf(run2[kk], fmaxf(v, run1[kk])); \
        if (v < run1[kk]) { ttix[kk] = tt; run1[kk] = v; } \
        run2[kk] = nr2; }
        FOLD(c0, 0) FOLD(c1, 1) FOLD(c2, 2) FOLD(c3, 3)
#undef FOLD
    }

    // ---- cross-half merge: chunk min r1c, winner tile T*, lower bound L on other tiles ----
#pragma unroll
    for (int k = 0; k < 4; k++) {
        float o1 = __shfl_xor(run1[k], 32, 64);
        float o2 = __shfl_xor(run2[k], 32, 64);
        int   ot = __shfl_xor(ttix[k], 32, 64);
        float lo1 = (lane < 32) ? run1[k] : o1;  int loT = (lane < 32) ? ttix[k] : ot;
        float lo2 = (lane < 32) ? run2[k] : o2;
        float hi1 = (lane < 32) ? o1 : run1[k];  int hiT = (lane < 32) ? ot : ttix[k];
        float hi2 = (lane < 32) ? o2 : run2[k];
        float r1c = fminf(lo1, hi1);
        int Tstar = (lo1 <= hi1) ? loT : hiT;
        float cl = (loT != Tstar) ? lo1 : lo2;
        float ch = (hiT != Tstar) ? hi1 : hi2;
        float L = fminf(cl, ch);
        if (lane < 32) {
            size_t qi = (size_t)(qb * 512 + wave * 128 + k * 32 + lane) * 64 + pc;
            pbvT[qi] = r1c;
            auxT[qi] = (__float_as_uint(L) & ~0xFu) | (unsigned)Tstar;
        }
    }
}

// ===================== K2: seg_pick_final (R17-validated; query coords from sorted out) =====================
// One block per segment, 16 waves. Per member j: query coords read from out[j*3..]
// (written by K1's scatter; == dpts[sorted_orig[j]*3..] bitwise — contiguous in j,
// replacing a scattered gather). Then the validated resolve: pbvT row -> butterfly
// min -> g1; ballot(v<=g1+EPS) -> chunk mask; per chunk, auxT narrowing
// (L > thr+SLACK -> scan tile T*, 32 pts) else full 512-pt scan; f32 filter ->
// exact f64 eval; lowest-index tie-break == full f64 argmin. Lane c<21 accumulates
// scores[nn][c] in f64, fixed (j,wave) order -> deterministic; block argmax
// (strict >) -> labels to original positions. argmax(sum) == argmax(mean).
__global__ __launch_bounds__(1024)
void k2_seg_pick(const float4* __restrict__ pts4,
                 const float* __restrict__ scores, const float* __restrict__ pbvT,
                 const unsigned* __restrict__ auxT,
                 const int* __restrict__ segbase, const int* __restrict__ sorted_orig,
                 float* __restrict__ out, int n, int m)
{
    __shared__ double wsum[16][C];
    __shared__ double total[C];
    __shared__ float lab;
    const int t = threadIdx.x, wave = t >> 6, lane = t & 63;
    const int s = blockIdx.x;
    const int base = segbase[s];
    const int end  = (s == NSEG - 1) ? m : segbase[s + 1];

    double acc = 0.0;                             // channel `lane` partial (lanes 0..20)
    for (int j = base + wave; j < end; j += 16) {
        int q = sorted_orig[j];
        float myv = pbvT[(size_t)q * 64 + lane];  // chunk `lane` min (coalesced 256B)
        float g1 = myv;
#pragma unroll
        for (int off = 1; off < 64; off <<= 1) g1 = fminf(g1, __shfl_xor(g1, off, 64));
        float thr = g1 + EPS_PICK;
        unsigned long long msk = __ballot(myv <= thr);   // bit pc == chunk qualifies

        float fx = out[j * 3 + 0], fy = out[j * 3 + 1], fz = out[j * 3 + 2];  // sorted coords
        float fm2x = -2.f * fx, fm2y = -2.f * fy, fm2z = -2.f * fz;
        double m2x = -2.0 * (double)fx, m2y = -2.0 * (double)fy, m2z = -2.0 * (double)fz;
        double best = 1e308; int bi = 0x7fffffff;
        while (msk) {
            int pc = __builtin_ctzll(msk); msk &= msk - 1;
            unsigned au = auxT[(size_t)q * 64 + pc];     // lane-uniform -> broadcast
            float L = __uint_as_float(au & ~0xFu);
            int Ts = (int)(au & 0xFu);
            if (L > thr + SLACK) {
                if (lane < 32) {                  // only tile T* can hold candidates
                    int i = pc * PPB + Ts * 32 + lane;
                    if (i < n) {
                        float4 p = pts4[i];
                        float v = fmaf(p.x, fm2x, fmaf(p.y, fm2y, fmaf(p.z, fm2z, p.w)));
                        if (v <= thr) {
                            double ps = (double)p.x * p.x + (double)p.y * p.y + (double)p.z * p.z;
                            double dv = fma((double)p.x, m2x, fma((double)p.y, m2y,
                                        fma((double)p.z, m2z, ps)));
                            if (dv < best || (dv == best && i < bi)) { best = dv; bi = i; }
                        }
                    }
                }
            } else {
                int pbase = pc * PPB + lane;      // full chunk scan (validated path)
#pragma unroll
                for (int r2 = 0; r2 < PPB / 64; r2++) {
                    int i = pbase + r2 * 64;
                    if (i < n) {
                        float4 p = pts4[i];
                        float v = fmaf(p.x, fm2x, fmaf(p.y, fm2y, fmaf(p.z, fm2z, p.w)));
                        if (v <= thr) {
                            double ps = (double)p.x * p.x + (double)p.y * p.y + (double)p.z * p.z;
                            double dv = fma((double)p.x, m2x, fma((double)p.y, m2y,
                                        fma((double)p.z, m2z, ps)));
                            if (dv < best || (dv == best && i < bi)) { best = dv; bi = i; }
                        }
                    }
                }
            }
        }
#pragma unroll
        for (int off = 32; off; off >>= 1) {
            double ov = __shfl_down(best, off, 64);
            int oi = __shfl_down(bi, off, 64);
            if (ov < best || (ov == best && oi < bi)) { best = ov; bi = oi; }
        }
        int bi0 = __shfl(bi, 0, 64);
        if (lane < C)
            acc += (double)scores[(size_t)bi0 * C + lane];
    }
    if (lane < C) wsum[wave][lane] = acc;
    __syncthreads();
    if (t < C) {
        double tv = 0.0;
#pragma unroll
        for (int w = 0; w < 16; w++) tv += wsum[w][t];   // fixed wave order
        total[t] = tv;
    }
    __syncthreads();
    if (t == 0) {
        double bv = total[0]; int best = 0;
        for (int c = 1; c < C; c++)
            if (total[c] > bv) { bv = total[c]; best = c; }  // strict >: first max wins
        lab = (float)best;
    }
    __syncthreads();
    float fb = lab;
    for (int j = base + t; j < end; j += 1024)    // labels in ORIGINAL order
        out[(size_t)m * 3 + sorted_orig[j]] = fb;
}

extern "C" void kernel_launch(void* const* d_in, const int* in_sizes, int n_in,
                              void* d_out, int out_size, void* d_ws, size_t ws_size,
                              hipStream_t stream) {
    const float* points = (const float*)d_in[0];
    const float* scores = (const float*)d_in[1];
    const float* dpts   = (const float*)d_in[2];
    const int*   sptids = (const int*)d_in[3];

    int n = in_sizes[0] / 3;          // 32768
    int m = in_sizes[2] / 3;          // 16384
    int NCH   = (m + 255) / 256;      // 64 scatter chunks
    int QB    = (m + 511) / 512;      // 32 query blocks
    int PCg   = (n + 511) / 512;      // 64 point chunks
    int MFMAB = QB * PCg;             // 2048 mfma blocks

    char* ws = (char*)d_ws;
    float4*   pts4        = (float4*)ws;    ws += (size_t)n * sizeof(float4);
    float*    pbvT        = (float*)ws;     ws += (size_t)m * 64 * sizeof(float);
    unsigned* auxT        = (unsigned*)ws;  ws += (size_t)m * 64 * sizeof(unsigned);
    int*      segbase     = (int*)ws;       ws += (size_t)NSEG * sizeof(int);
    int*      sorted_orig = (int*)ws;       ws += (size_t)m * sizeof(int);

    k1_mfma_scatter<<<NCH + MFMAB, 256, 0, stream>>>(points, dpts, sptids,
                                                     pts4, pbvT, auxT, segbase,
                                                     sorted_orig, (float*)d_out, n, m, NCH);
    k2_seg_pick<<<NSEG, 1024, 0, stream>>>(pts4, scores, pbvT, auxT,
                                           segbase, sorted_orig, (float*)d_out, n, m);
}